// Round 11
// baseline (343.602 us; speedup 1.0000x reference)
//
#include <hip/hip_runtime.h>
#include <hip/hip_bf16.h>
#include <cstdint>
#include <cstddef>

#define FIN      128
#define HGAT_H   4
#define HGAT_C   64
#define HGAT_HC  256
#define NGRAPHS  64
#define NACT     32
#define LOG2E    1.4426950408889634f

typedef unsigned int   uint32;
typedef unsigned short ushort_t;

using short8 = __attribute__((ext_vector_type(8))) short;
using u16x8  = __attribute__((ext_vector_type(8))) ushort_t;
using f32x4  = __attribute__((ext_vector_type(4))) float;
using f32x2  = __attribute__((ext_vector_type(2))) float;

__device__ __forceinline__ float bf2f(ushort_t u) {
    return __uint_as_float(((uint32)u) << 16);
}
__device__ __forceinline__ float bflo(uint32 q) {
    return __uint_as_float(q << 16);
}
__device__ __forceinline__ float bfhi(uint32 q) {
    return __uint_as_float(q & 0xFFFF0000u);
}
__device__ __forceinline__ ushort_t f2bf(float f) {
    __hip_bfloat16 h = __float2bfloat16(f);   // RNE
    return *reinterpret_cast<ushort_t*>(&h);
}

// ---------------------------------------------------------------------------
// Both weight transposes/casts in one launch.
// ---------------------------------------------------------------------------
__global__ __launch_bounds__(256) void wcast2_kernel(
    const float* __restrict__ W1, const float* __restrict__ W2,
    ushort_t* __restrict__ Wt1, ushort_t* __restrict__ Wt2)
{
    const int idx = blockIdx.x * 256 + threadIdx.x;
    const int n1 = FIN * HGAT_HC;
    const int n2 = HGAT_HC * HGAT_HC;
    if (idx < n1) {
        const int k = idx >> 8, c = idx & 255;
        Wt1[(size_t)c * FIN + k] = f2bf(W1[idx]);
    } else if (idx < n1 + n2) {
        const int j = idx - n1;
        const int k = j >> 8, c = j & 255;
        Wt2[(size_t)c * HGAT_HC + k] = f2bf(W2[j]);
    }
}

// ---------------------------------------------------------------------------
// Fold attention vectors through W:  attB[k][j] = sum_c W[k][h*64+c]*att[h][c]
// j = h*2 + (0:src | 1:dst).  Stored transposed as attBt[16][K] bf16 with
// SPLIT hi/lo: rows 0..7 = bf16(v), rows 8..15 = bf16(v - f32(hi)).
// One extra MFMA B-tile then yields exact-ish a_src/a_dst dots.
// ---------------------------------------------------------------------------
__device__ __forceinline__ void att_fold_one(
    const float* __restrict__ W, const float* __restrict__ as,
    const float* __restrict__ ad, ushort_t* __restrict__ attBt,
    int K, int idx)
{
    const int k = idx >> 3, j = idx & 7;
    const int h = j >> 1;
    const float* av = (j & 1) ? ad : as;
    float s = 0.f;
#pragma unroll 8
    for (int c = 0; c < HGAT_C; ++c)
        s += W[(size_t)k * HGAT_HC + h * 64 + c] * av[h * 64 + c];
    const ushort_t hi = f2bf(s);
    const float    lo = s - bf2f(hi);
    attBt[(size_t)j * K + k]       = hi;
    attBt[(size_t)(j + 8) * K + k] = f2bf(lo);
}

__global__ __launch_bounds__(256) void att_fold_kernel(
    const float* __restrict__ W1, const float* __restrict__ as1,
    const float* __restrict__ ad1, const float* __restrict__ W2,
    const float* __restrict__ as2, const float* __restrict__ ad2,
    ushort_t* __restrict__ attBt1, ushort_t* __restrict__ attBt2)
{
    const int idx = blockIdx.x * 256 + threadIdx.x;
    if (idx < FIN * 8)
        att_fold_one(W1, as1, ad1, attBt1, FIN, idx);
    else if (idx < FIN * 8 + HGAT_HC * 8)
        att_fold_one(W2, as2, ad2, attBt2, HGAT_HC, idx - FIN * 8);
}

// ---------------------------------------------------------------------------
// MFMA GEMM + attention epilogue.  C[M,256] = A[M,K] @ Wt^T.
// Block = 64 rows, 4 waves; wave w owns rows [w*16, +16). A frags in
// registers for the whole kernel. Per head the 64xK B panel lives in LDS
// (stride K+8), next head's panel register-prefetched under the MFMAs.
// Attention dots via ONE extra MFMA against the 16-col attBt tile
// (hi/lo split), combined with a single shfl_xor(8) -- no shfl-reduce tree.
// mfma_f32_16x16x32_bf16 D map: col=lane&15, row=(lane>>4)*4+reg.
// ---------------------------------------------------------------------------
template <int K, bool AF32>
__global__ __launch_bounds__(256) void gemm_mfma_att_kernel(
    const void* __restrict__ Av, const ushort_t* __restrict__ Bt,
    const ushort_t* __restrict__ attBt, ushort_t* __restrict__ Cb,
    float* __restrict__ a_src, float* __restrict__ a_dst, int M)
{
    constexpr int KK   = K / 32;
    constexpr int NPF  = K / 32;
    constexpr int BSTR = K + 8;
    __shared__ ushort_t Bs[64 * BSTR];
    __shared__ ushort_t AttS[16 * BSTR];

    const int t  = threadIdx.x;
    const int w  = t >> 6;
    const int l  = t & 63;
    const int lg = l >> 4;
    const int lr = l & 15;
    const int rowbase = blockIdx.x * 64 + w * 16;

    const int srow  = t & 63;
    const int cbase = (t >> 6) * (K / 4);

    // ---- A fragments (A read once from HBM)
    short8 af[KK];
    {
        const int arow = rowbase + lr;
        const int gr   = arow < M ? arow : M - 1;
        if (AF32) {
            const float* Ap = (const float*)Av + (size_t)gr * K;
#pragma unroll
            for (int kk = 0; kk < KK; ++kk) {
                const float4 v0 = *reinterpret_cast<const float4*>(Ap + kk * 32 + lg * 8);
                const float4 v1 = *reinterpret_cast<const float4*>(Ap + kk * 32 + lg * 8 + 4);
                short8 s;
                s[0] = (short)f2bf(v0.x); s[1] = (short)f2bf(v0.y);
                s[2] = (short)f2bf(v0.z); s[3] = (short)f2bf(v0.w);
                s[4] = (short)f2bf(v1.x); s[5] = (short)f2bf(v1.y);
                s[6] = (short)f2bf(v1.z); s[7] = (short)f2bf(v1.w);
                af[kk] = s;
            }
        } else {
            const ushort_t* Ap = (const ushort_t*)Av + (size_t)gr * K;
#pragma unroll
            for (int kk = 0; kk < KK; ++kk)
                af[kk] = *reinterpret_cast<const short8*>(Ap + kk * 32 + lg * 8);
        }
    }

    // ---- stage attBt tile + head-0 B panel
    {
        const int r  = t & 15;
        const int cb = (t >> 4) * (K / 16);
        const ushort_t* src = attBt + (size_t)r * K + cb;
        ushort_t*       dst = &AttS[r * BSTR + cb];
#pragma unroll
        for (int j = 0; j < K / 128; ++j)
            *reinterpret_cast<u16x8*>(dst + j * 8) =
                *reinterpret_cast<const u16x8*>(src + j * 8);
    }
    {
        const ushort_t* src = Bt + (size_t)srow * K + cbase;
        ushort_t*       dst = &Bs[srow * BSTR + cbase];
#pragma unroll
        for (int j = 0; j < NPF; ++j)
            *reinterpret_cast<u16x8*>(dst + j * 8) =
                *reinterpret_cast<const u16x8*>(src + j * 8);
    }
    __syncthreads();

    // ---- attention dots: one MFMA chain over the 16-col att tile
    {
        f32x4 aacc = {0.f, 0.f, 0.f, 0.f};
#pragma unroll
        for (int kk = 0; kk < KK; ++kk) {
            const short8 bfr = *reinterpret_cast<const short8*>(
                &AttS[lr * BSTR + kk * 32 + lg * 8]);
            aacc = __builtin_amdgcn_mfma_f32_16x16x32_bf16(af[kk], bfr, aacc, 0, 0, 0);
        }
#pragma unroll
        for (int reg = 0; reg < 4; ++reg) {
            const int gm = rowbase + lg * 4 + reg;
            const float v = aacc[reg] + __shfl_xor(aacc[reg], 8);   // hi + lo
            if (lr < 8 && gm < M) {
                const int hh = lr >> 1;
                if (lr & 1) a_dst[gm * 4 + hh] = v * LOG2E;
                else        a_src[gm * 4 + hh] = v * LOG2E;
            }
        }
    }

    // ---- head loop
    u16x8 pf[NPF];
#pragma unroll
    for (int head = 0; head < HGAT_H; ++head) {
        if (head < HGAT_H - 1) {
            const ushort_t* src =
                Bt + ((size_t)(head + 1) * 64 + srow) * K + cbase;
#pragma unroll
            for (int j = 0; j < NPF; ++j)
                pf[j] = *reinterpret_cast<const u16x8*>(src + j * 8);
        }

        f32x4 acc[4];
#pragma unroll
        for (int ct = 0; ct < 4; ++ct) acc[ct] = {0.f, 0.f, 0.f, 0.f};

#pragma unroll
        for (int kk = 0; kk < KK; ++kk) {
            short8 bfr[4];
#pragma unroll
            for (int ct = 0; ct < 4; ++ct)
                bfr[ct] = *reinterpret_cast<const short8*>(
                    &Bs[(ct * 16 + lr) * BSTR + kk * 32 + lg * 8]);
#pragma unroll
            for (int ct = 0; ct < 4; ++ct)
                acc[ct] = __builtin_amdgcn_mfma_f32_16x16x32_bf16(
                    af[kk], bfr[ct], acc[ct], 0, 0, 0);
        }

        const int n0 = head * 64;
#pragma unroll
        for (int reg = 0; reg < 4; ++reg) {
            const int gm = rowbase + lg * 4 + reg;
            if (gm < M) {
#pragma unroll
                for (int ct = 0; ct < 4; ++ct)
                    Cb[(size_t)gm * HGAT_HC + n0 + ct * 16 + lr] =
                        f2bf(acc[ct][reg]);
            }
        }

        __syncthreads();   // all waves done reading Bs
        if (head < HGAT_H - 1) {
            ushort_t* dst = &Bs[srow * BSTR + cbase];
#pragma unroll
            for (int j = 0; j < NPF; ++j)
                *reinterpret_cast<u16x8*>(dst + j * 8) = pf[j];
            __syncthreads();   // committed panel visible
        }
    }
}

// ---------------------------------------------------------------------------
// CSR build: degree count, hierarchical scan, cursor fill.
// ---------------------------------------------------------------------------
__global__ __launch_bounds__(256) void count_deg_kernel(
    const int* __restrict__ ei, int* __restrict__ deg, int E)
{
    const int e = blockIdx.x * 256 + threadIdx.x;
    if (e < E) atomicAdd(&deg[ei[E + e]], 1);
}

__global__ __launch_bounds__(256) void block_sum_kernel(
    const int* __restrict__ deg, int* __restrict__ bsum, int N)
{
    __shared__ int sm[256];
    const int idx = blockIdx.x * 256 + threadIdx.x;
    sm[threadIdx.x] = idx < N ? deg[idx] : 0;
    __syncthreads();
#pragma unroll
    for (int off = 128; off; off >>= 1) {
        if (threadIdx.x < off) sm[threadIdx.x] += sm[threadIdx.x + off];
        __syncthreads();
    }
    if (threadIdx.x == 0) bsum[blockIdx.x] = sm[0];
}

__global__ __launch_bounds__(256) void scan_bsums_kernel(
    int* __restrict__ bsum, int NB)
{
    __shared__ int sm[256];
    const int t = threadIdx.x;
    int v = t < NB ? bsum[t] : 0;
    sm[t] = v;
    __syncthreads();
#pragma unroll
    for (int off = 1; off < 256; off <<= 1) {
        const int u = (t >= off) ? sm[t - off] : 0;
        __syncthreads();
        sm[t] += u;
        __syncthreads();
    }
    if (t < NB) bsum[t] = sm[t] - v;   // exclusive
}

__global__ __launch_bounds__(256) void rowptr_kernel(
    const int* __restrict__ deg, const int* __restrict__ bsum,
    int* __restrict__ rowptr, int* __restrict__ cursor, int N)
{
    __shared__ int sm[256];
    const int t   = threadIdx.x;
    const int idx = blockIdx.x * 256 + t;
    const int v   = idx < N ? deg[idx] : 0;
    sm[t] = v;
    __syncthreads();
#pragma unroll
    for (int off = 1; off < 256; off <<= 1) {
        const int u = (t >= off) ? sm[t - off] : 0;
        __syncthreads();
        sm[t] += u;
        __syncthreads();
    }
    const int base = bsum[blockIdx.x];
    if (idx < N) {
        const int r = base + sm[t] - v;
        rowptr[idx] = r;
        cursor[idx] = r;
    }
    if (idx == N - 1) rowptr[N] = base + sm[t];
}

__global__ __launch_bounds__(256) void fill_csr_kernel(
    const int* __restrict__ ei, int* __restrict__ cursor,
    int* __restrict__ colsrc, int E)
{
    const int e = blockIdx.x * 256 + threadIdx.x;
    if (e >= E) return;
    const int d = ei[E + e];
    const int pos = atomicAdd(&cursor[d], 1);
    colsrc[pos] = ei[e];
}

// ---------------------------------------------------------------------------
// CSR aggregate, wave per dst node, SCALARIZED: d is wave-uniform, so
// rowptr/colsrc/a_src/a_dst loads and the hb row base become s_loads /
// saddr-form VMEM (readfirstlane forces uniformity). Per-edge vector work:
// select-by-h (3 cndmask) + leaky + exp2 + 2 pk_fma + unpack.
// MODE 0: concat + bias + ELU -> bf16 out[N,256].
// MODE 1: head-mean + bias + ELU -> bf16 out[N,64].
// ---------------------------------------------------------------------------
template <int MODE>
__global__ __launch_bounds__(256) void aggregate_csr_kernel(
    const int* __restrict__ rowptr, const int* __restrict__ colsrc,
    const ushort_t* __restrict__ hb, const float* __restrict__ a_src,
    const float* __restrict__ a_dst, const float* __restrict__ bias,
    ushort_t* __restrict__ out, int N)
{
    const int dd = (blockIdx.x * 256 + threadIdx.x) >> 6;
    if (dd >= N) return;
    const int d    = __builtin_amdgcn_readfirstlane(dd);
    const int lane = threadIdx.x & 63;
    const int h  = lane >> 4;
    const int c0 = lane * 4;

    const float4 adr = *reinterpret_cast<const float4*>(a_dst + d * 4);
    const float ad = h == 0 ? adr.x : h == 1 ? adr.y : h == 2 ? adr.z : adr.w;

    f32x2 acc01 = {0.f, 0.f}, acc23 = {0.f, 0.f};
    float den = 0.f;

    const int beg = rowptr[d], end = rowptr[d + 1];
    int i = beg;
    for (; i + 4 <= end; i += 4) {
        int sv[4];
#pragma unroll
        for (int j = 0; j < 4; ++j) sv[j] = colsrc[i + j];
        float av[4];
#pragma unroll
        for (int j = 0; j < 4; ++j) {
            const float4 ar = *reinterpret_cast<const float4*>(a_src + sv[j] * 4);
            av[j] = h == 0 ? ar.x : h == 1 ? ar.y : h == 2 ? ar.z : ar.w;
        }
        uint2 qv[4];
#pragma unroll
        for (int j = 0; j < 4; ++j)
            qv[j] = *reinterpret_cast<const uint2*>(hb + (size_t)sv[j] * HGAT_HC + c0);
#pragma unroll
        for (int j = 0; j < 4; ++j) {
            float ee = av[j] + ad;
            ee = fmaxf(ee, 0.2f * ee);
            const float wgt = __builtin_amdgcn_exp2f(ee);
            const f32x2 w2 = {wgt, wgt};
            const f32x2 p01 = {bflo(qv[j].x), bfhi(qv[j].x)};
            const f32x2 p23 = {bflo(qv[j].y), bfhi(qv[j].y)};
            acc01 += w2 * p01;
            acc23 += w2 * p23;
            den += wgt;
        }
    }
    for (; i < end; ++i) {
        const int s = colsrc[i];
        const float4 ar = *reinterpret_cast<const float4*>(a_src + s * 4);
        const float a = h == 0 ? ar.x : h == 1 ? ar.y : h == 2 ? ar.z : ar.w;
        float ee = a + ad;
        ee = fmaxf(ee, 0.2f * ee);
        const float wgt = __builtin_amdgcn_exp2f(ee);
        const uint2 q = *reinterpret_cast<const uint2*>(hb + (size_t)s * HGAT_HC + c0);
        const f32x2 w2 = {wgt, wgt};
        const f32x2 p01 = {bflo(q.x), bfhi(q.x)};
        const f32x2 p23 = {bflo(q.y), bfhi(q.y)};
        acc01 += w2 * p01;
        acc23 += w2 * p23;
        den += wgt;
    }
    {   // self loop (s == d, uniform)
        const float4 ar = *reinterpret_cast<const float4*>(a_src + d * 4);
        const float a = h == 0 ? ar.x : h == 1 ? ar.y : h == 2 ? ar.z : ar.w;
        float ee = a + ad;
        ee = fmaxf(ee, 0.2f * ee);
        const float wgt = __builtin_amdgcn_exp2f(ee);
        const uint2 q = *reinterpret_cast<const uint2*>(hb + (size_t)d * HGAT_HC + c0);
        const f32x2 w2 = {wgt, wgt};
        const f32x2 p01 = {bflo(q.x), bfhi(q.x)};
        const f32x2 p23 = {bflo(q.y), bfhi(q.y)};
        acc01 += w2 * p01;
        acc23 += w2 * p23;
        den += wgt;
    }

    const float inv = 1.0f / den;
    float4 v = {acc01.x * inv, acc01.y * inv, acc23.x * inv, acc23.y * inv};

    if (MODE == 0) {
        v.x += bias[c0 + 0]; v.y += bias[c0 + 1];
        v.z += bias[c0 + 2]; v.w += bias[c0 + 3];
        v.x = v.x > 0.f ? v.x : expm1f(v.x);
        v.y = v.y > 0.f ? v.y : expm1f(v.y);
        v.z = v.z > 0.f ? v.z : expm1f(v.z);
        v.w = v.w > 0.f ? v.w : expm1f(v.w);
        ushort4 u;
        u.x = f2bf(v.x); u.y = f2bf(v.y); u.z = f2bf(v.z); u.w = f2bf(v.w);
        *reinterpret_cast<ushort4*>(&out[(size_t)d * HGAT_HC + c0]) = u;
    } else {
        v.x += __shfl_xor(v.x, 16); v.x += __shfl_xor(v.x, 32);
        v.y += __shfl_xor(v.y, 16); v.y += __shfl_xor(v.y, 32);
        v.z += __shfl_xor(v.z, 16); v.z += __shfl_xor(v.z, 32);
        v.w += __shfl_xor(v.w, 16); v.w += __shfl_xor(v.w, 32);
        if (lane < 16) {
            const int c = lane * 4;
            float4 r;
            r.x = 0.25f * v.x + bias[c + 0];
            r.y = 0.25f * v.y + bias[c + 1];
            r.z = 0.25f * v.z + bias[c + 2];
            r.w = 0.25f * v.w + bias[c + 3];
            r.x = r.x > 0.f ? r.x : expm1f(r.x);
            r.y = r.y > 0.f ? r.y : expm1f(r.y);
            r.z = r.z > 0.f ? r.z : expm1f(r.z);
            r.w = r.w > 0.f ? r.w : expm1f(r.w);
            ushort4 u;
            u.x = f2bf(r.x); u.y = f2bf(r.y); u.z = f2bf(r.z); u.w = f2bf(r.w);
            *reinterpret_cast<ushort4*>(&out[(size_t)d * HGAT_C + c]) = u;
        }
    }
}

// ---------------------------------------------------------------------------
// Pool stage A: 8 node-slices per graph -> partial sums.
// ---------------------------------------------------------------------------
__device__ __forceinline__ int lower_bound_batch(
    const int* __restrict__ batch, int N, int key)
{
    int lo = 0, hi = N;
    while (lo < hi) {
        const int mid = (lo + hi) >> 1;
        if (batch[mid] < key) lo = mid + 1; else hi = mid;
    }
    return lo;
}

__global__ __launch_bounds__(256) void pool_partial_kernel(
    const ushort_t* __restrict__ hfin, const int* __restrict__ batch,
    float* __restrict__ partial, int N)
{
    const int g   = blockIdx.x >> 3;
    const int s   = blockIdx.x & 7;
    const int t   = threadIdx.x;
    const int c   = t & 63;
    const int sub = t >> 6;

    const int beg = lower_bound_batch(batch, N, g);
    const int end = lower_bound_batch(batch, N, g + 1);
    const int len = end - beg;
    const int sl  = (len + 7) >> 3;
    const int sb  = beg + s * sl;
    const int se  = sb + sl < end ? sb + sl : end;

    float acc = 0.f;
    for (int n = sb + sub; n < se; n += 4)
        acc += bf2f(hfin[(size_t)n * HGAT_C + c]);

    __shared__ float sm[256];
    sm[t] = acc;
    __syncthreads();
    if (sub == 0)
        partial[(size_t)(g * 8 + s) * HGAT_C + c] =
            sm[c] + sm[64 + c] + sm[128 + c] + sm[192 + c];
}

// ---------------------------------------------------------------------------
// Pool stage B fused with final linear: one block per graph.
// ---------------------------------------------------------------------------
__global__ __launch_bounds__(64) void pool_final_fused_kernel(
    const float* __restrict__ partial, const int* __restrict__ batch,
    const float* __restrict__ Wa, const float* __restrict__ ba,
    float* __restrict__ out, int N)
{
    const int g = blockIdx.x;
    const int c = threadIdx.x;
    const int beg = lower_bound_batch(batch, N, g);
    const int end = lower_bound_batch(batch, N, g + 1);
    float s = 0.f;
#pragma unroll
    for (int k = 0; k < 8; ++k)
        s += partial[(size_t)(g * 8 + k) * HGAT_C + c];
    s /= fmaxf((float)(end - beg), 1.0f);

    __shared__ float pr[HGAT_C];
    pr[c] = s;
    __syncthreads();
    if (c < NACT) {
        float o = ba[c];
#pragma unroll
        for (int cc = 0; cc < HGAT_C; ++cc)
            o += pr[cc] * Wa[cc * NACT + c];
        out[g * NACT + c] = o;
    }
}

// ---------------------------------------------------------------------------
extern "C" void kernel_launch(void* const* d_in, const int* in_sizes, int n_in,
                              void* d_out, int out_size, void* d_ws, size_t ws_size,
                              hipStream_t stream)
{
    const float* x     = (const float*)d_in[0];
    const int*   ei    = (const int*)d_in[1];
    const int*   batch = (const int*)d_in[2];
    const float* W1    = (const float*)d_in[5];
    const float* as1   = (const float*)d_in[6];
    const float* ad1   = (const float*)d_in[7];
    const float* b1    = (const float*)d_in[8];
    const float* W2    = (const float*)d_in[9];
    const float* as2   = (const float*)d_in[10];
    const float* ad2   = (const float*)d_in[11];
    const float* b2    = (const float*)d_in[12];
    const float* Wa    = (const float*)d_in[13];
    const float* ba    = (const float*)d_in[14];

    const int N = in_sizes[0] / FIN;
    const int E = in_sizes[1] / 2;

    char* ws = (char*)d_ws;
    size_t off = 0;
    auto alloc = [&](size_t bytes) -> void* {
        void* p = ws + off;
        off += (bytes + 255) & ~(size_t)255;
        return p;
    };
    ushort_t* hb      = (ushort_t*)alloc((size_t)N * HGAT_HC * 2);
    ushort_t* hpost   = (ushort_t*)alloc((size_t)N * HGAT_HC * 2);
    ushort_t* Wt1     = (ushort_t*)alloc((size_t)FIN * HGAT_HC * 2);
    ushort_t* Wt2     = (ushort_t*)alloc((size_t)HGAT_HC * HGAT_HC * 2);
    ushort_t* attBt1  = (ushort_t*)alloc((size_t)16 * FIN * 2);
    ushort_t* attBt2  = (ushort_t*)alloc((size_t)16 * HGAT_HC * 2);
    float*    a_src   = (float*)alloc((size_t)N * 4 * 4);
    float*    a_dst   = (float*)alloc((size_t)N * 4 * 4);
    int*      rowptr  = (int*)alloc((size_t)(N + 1) * 4);
    int*      colsrc  = (int*)alloc((size_t)E * 4);
    int*      deg     = (int*)alloc((size_t)N * 4);
    int*      cursor  = (int*)alloc((size_t)N * 4);
    int*      bsum    = (int*)alloc(256 * 4);
    float*    partial = (float*)alloc((size_t)NGRAPHS * 8 * HGAT_C * 4);
    ushort_t* hfin    = hpost;
    (void)ws_size; (void)n_in; (void)out_size;

    const int gemmBlocks     = (N + 63) / 64;
    const int edgeBlocks     = (E + 255) / 256;
    const int nodeWaveBlocks = (N + 3) / 4;
    const int NB             = (N + 255) / 256;

    // ---------------- CSR build ----------------
    hipMemsetAsync(deg, 0, (size_t)N * 4, stream);
    count_deg_kernel<<<edgeBlocks, 256, 0, stream>>>(ei, deg, E);
    block_sum_kernel<<<NB, 256, 0, stream>>>(deg, bsum, N);
    scan_bsums_kernel<<<1, 256, 0, stream>>>(bsum, NB);
    rowptr_kernel<<<NB, 256, 0, stream>>>(deg, bsum, rowptr, cursor, N);
    fill_csr_kernel<<<edgeBlocks, 256, 0, stream>>>(ei, cursor, colsrc, E);

    // ---------------- weight transpose/cast + att fold ----------------
    wcast2_kernel<<<(FIN * HGAT_HC + HGAT_HC * HGAT_HC + 255) / 256, 256, 0, stream>>>(
        W1, W2, Wt1, Wt2);
    att_fold_kernel<<<((FIN + HGAT_HC) * 8 + 255) / 256, 256, 0, stream>>>(
        W1, as1, ad1, W2, as2, ad2, attBt1, attBt2);

    // ---------------- layer 1 ----------------
    gemm_mfma_att_kernel<FIN, true><<<gemmBlocks, 256, 0, stream>>>(
        x, Wt1, attBt1, hb, a_src, a_dst, N);
    aggregate_csr_kernel<0><<<nodeWaveBlocks, 256, 0, stream>>>(
        rowptr, colsrc, hb, a_src, a_dst, b1, hpost, N);

    // ---------------- layer 2 ----------------
    gemm_mfma_att_kernel<HGAT_HC, false><<<gemmBlocks, 256, 0, stream>>>(
        hpost, Wt2, attBt2, hb, a_src, a_dst, N);
    aggregate_csr_kernel<1><<<nodeWaveBlocks, 256, 0, stream>>>(
        rowptr, colsrc, hb, a_src, a_dst, b2, hfin, N);

    // ---------------- pool + final ----------------
    pool_partial_kernel<<<NGRAPHS * 8, 256, 0, stream>>>(hfin, batch, partial, N);
    pool_final_fused_kernel<<<NGRAPHS, 64, 0, stream>>>(
        partial, batch, Wa, ba, (float*)d_out, N);
}

// Round 12
// 312.826 us; speedup vs baseline: 1.0984x; 1.0984x over previous
//
#include <hip/hip_runtime.h>
#include <hip/hip_bf16.h>
#include <cstdint>
#include <cstddef>

#define FIN      128
#define HGAT_H   4
#define HGAT_C   64
#define HGAT_HC  256
#define NGRAPHS  64
#define NACT     32
#define LOG2E    1.4426950408889634f

typedef unsigned int   uint32;
typedef unsigned short ushort_t;

using short8 = __attribute__((ext_vector_type(8))) short;
using u16x8  = __attribute__((ext_vector_type(8))) ushort_t;
using f32x4  = __attribute__((ext_vector_type(4))) float;
using f32x2  = __attribute__((ext_vector_type(2))) float;

__device__ __forceinline__ float bf2f(ushort_t u) {
    return __uint_as_float(((uint32)u) << 16);
}
__device__ __forceinline__ float bflo(uint32 q) {
    return __uint_as_float(q << 16);
}
__device__ __forceinline__ float bfhi(uint32 q) {
    return __uint_as_float(q & 0xFFFF0000u);
}
__device__ __forceinline__ ushort_t f2bf(float f) {
    __hip_bfloat16 h = __float2bfloat16(f);   // RNE
    return *reinterpret_cast<ushort_t*>(&h);
}

// ---------------------------------------------------------------------------
// Both weight transposes/casts in one launch.
// ---------------------------------------------------------------------------
__global__ __launch_bounds__(256) void wcast2_kernel(
    const float* __restrict__ W1, const float* __restrict__ W2,
    ushort_t* __restrict__ Wt1, ushort_t* __restrict__ Wt2)
{
    const int idx = blockIdx.x * 256 + threadIdx.x;
    const int n1 = FIN * HGAT_HC;
    const int n2 = HGAT_HC * HGAT_HC;
    if (idx < n1) {
        const int k = idx >> 8, c = idx & 255;
        Wt1[(size_t)c * FIN + k] = f2bf(W1[idx]);
    } else if (idx < n1 + n2) {
        const int j = idx - n1;
        const int k = j >> 8, c = j & 255;
        Wt2[(size_t)c * HGAT_HC + k] = f2bf(W2[j]);
    }
}

// ---------------------------------------------------------------------------
// Fold attention vectors through W:  attB[k][j] = sum_c W[k][h*64+c]*att[h][c]
// j = h*2 + (0:src | 1:dst).  Stored transposed as attBt[16][K] bf16 with
// SPLIT hi/lo: rows 0..7 = bf16(v), rows 8..15 = bf16(v - f32(hi)).
// ---------------------------------------------------------------------------
__device__ __forceinline__ void att_fold_one(
    const float* __restrict__ W, const float* __restrict__ as,
    const float* __restrict__ ad, ushort_t* __restrict__ attBt,
    int K, int idx)
{
    const int k = idx >> 3, j = idx & 7;
    const int h = j >> 1;
    const float* av = (j & 1) ? ad : as;
    float s = 0.f;
#pragma unroll 8
    for (int c = 0; c < HGAT_C; ++c)
        s += W[(size_t)k * HGAT_HC + h * 64 + c] * av[h * 64 + c];
    const ushort_t hi = f2bf(s);
    const float    lo = s - bf2f(hi);
    attBt[(size_t)j * K + k]       = hi;
    attBt[(size_t)(j + 8) * K + k] = f2bf(lo);
}

__global__ __launch_bounds__(256) void att_fold_kernel(
    const float* __restrict__ W1, const float* __restrict__ as1,
    const float* __restrict__ ad1, const float* __restrict__ W2,
    const float* __restrict__ as2, const float* __restrict__ ad2,
    ushort_t* __restrict__ attBt1, ushort_t* __restrict__ attBt2)
{
    const int idx = blockIdx.x * 256 + threadIdx.x;
    if (idx < FIN * 8)
        att_fold_one(W1, as1, ad1, attBt1, FIN, idx);
    else if (idx < FIN * 8 + HGAT_HC * 8)
        att_fold_one(W2, as2, ad2, attBt2, HGAT_HC, idx - FIN * 8);
}

// ---------------------------------------------------------------------------
// MFMA GEMM + attention epilogue.  C[M,256] = A[M,K] @ Wt^T.
// Block = 64 rows, 4 waves. A frags in registers for the whole kernel.
// Per head the 64xK B panel lives in LDS (stride K+8), next head's panel
// register-prefetched under the MFMAs. Attention dots via one extra MFMA
// against the hi/lo-split attBt tile + single shfl_xor(8).
// C store: stage the 64x64 bf16 tile in LDS (stride 72), copy out as
// u16x8 rows (2 coalesced 16B stores/thread/head vs 16 scalar 2B stores).
// mfma_f32_16x16x32_bf16 D map: col=lane&15, row=(lane>>4)*4+reg.
// ---------------------------------------------------------------------------
template <int K, bool AF32>
__global__ __launch_bounds__(256) void gemm_mfma_att_kernel(
    const void* __restrict__ Av, const ushort_t* __restrict__ Bt,
    const ushort_t* __restrict__ attBt, ushort_t* __restrict__ Cb,
    float* __restrict__ a_src, float* __restrict__ a_dst, int M)
{
    constexpr int KK   = K / 32;
    constexpr int NPF  = K / 32;
    constexpr int BSTR = K + 8;
    constexpr int CSTR = 72;            // 144B row stride, 16B-aligned
    __shared__ ushort_t Bs[64 * BSTR];
    __shared__ ushort_t AttS[16 * BSTR];
    __shared__ ushort_t Cs[64 * CSTR];

    const int t  = threadIdx.x;
    const int w  = t >> 6;
    const int l  = t & 63;
    const int lg = l >> 4;
    const int lr = l & 15;
    const int rowbase = blockIdx.x * 64 + w * 16;

    const int srow  = t & 63;
    const int cbase = (t >> 6) * (K / 4);

    // ---- A fragments (A read once from HBM)
    short8 af[KK];
    {
        const int arow = rowbase + lr;
        const int gr   = arow < M ? arow : M - 1;
        if (AF32) {
            const float* Ap = (const float*)Av + (size_t)gr * K;
#pragma unroll
            for (int kk = 0; kk < KK; ++kk) {
                const float4 v0 = *reinterpret_cast<const float4*>(Ap + kk * 32 + lg * 8);
                const float4 v1 = *reinterpret_cast<const float4*>(Ap + kk * 32 + lg * 8 + 4);
                short8 s;
                s[0] = (short)f2bf(v0.x); s[1] = (short)f2bf(v0.y);
                s[2] = (short)f2bf(v0.z); s[3] = (short)f2bf(v0.w);
                s[4] = (short)f2bf(v1.x); s[5] = (short)f2bf(v1.y);
                s[6] = (short)f2bf(v1.z); s[7] = (short)f2bf(v1.w);
                af[kk] = s;
            }
        } else {
            const ushort_t* Ap = (const ushort_t*)Av + (size_t)gr * K;
#pragma unroll
            for (int kk = 0; kk < KK; ++kk)
                af[kk] = *reinterpret_cast<const short8*>(Ap + kk * 32 + lg * 8);
        }
    }

    // ---- stage attBt tile + head-0 B panel
    {
        const int r  = t & 15;
        const int cb = (t >> 4) * (K / 16);
        const ushort_t* src = attBt + (size_t)r * K + cb;
        ushort_t*       dst = &AttS[r * BSTR + cb];
#pragma unroll
        for (int j = 0; j < K / 128; ++j)
            *reinterpret_cast<u16x8*>(dst + j * 8) =
                *reinterpret_cast<const u16x8*>(src + j * 8);
    }
    {
        const ushort_t* src = Bt + (size_t)srow * K + cbase;
        ushort_t*       dst = &Bs[srow * BSTR + cbase];
#pragma unroll
        for (int j = 0; j < NPF; ++j)
            *reinterpret_cast<u16x8*>(dst + j * 8) =
                *reinterpret_cast<const u16x8*>(src + j * 8);
    }
    __syncthreads();

    // ---- attention dots: one MFMA chain over the 16-col att tile
    {
        f32x4 aacc = {0.f, 0.f, 0.f, 0.f};
#pragma unroll
        for (int kk = 0; kk < KK; ++kk) {
            const short8 bfr = *reinterpret_cast<const short8*>(
                &AttS[lr * BSTR + kk * 32 + lg * 8]);
            aacc = __builtin_amdgcn_mfma_f32_16x16x32_bf16(af[kk], bfr, aacc, 0, 0, 0);
        }
#pragma unroll
        for (int reg = 0; reg < 4; ++reg) {
            const int gm = rowbase + lg * 4 + reg;
            const float v = aacc[reg] + __shfl_xor(aacc[reg], 8);   // hi + lo
            if (lr < 8 && gm < M) {
                const int hh = lr >> 1;
                if (lr & 1) a_dst[gm * 4 + hh] = v * LOG2E;
                else        a_src[gm * 4 + hh] = v * LOG2E;
            }
        }
    }

    // ---- head loop
    u16x8 pf[NPF];
#pragma unroll
    for (int head = 0; head < HGAT_H; ++head) {
        if (head < HGAT_H - 1) {
            const ushort_t* src =
                Bt + ((size_t)(head + 1) * 64 + srow) * K + cbase;
#pragma unroll
            for (int j = 0; j < NPF; ++j)
                pf[j] = *reinterpret_cast<const u16x8*>(src + j * 8);
        }

        f32x4 acc[4];
#pragma unroll
        for (int ct = 0; ct < 4; ++ct) acc[ct] = {0.f, 0.f, 0.f, 0.f};

#pragma unroll
        for (int kk = 0; kk < KK; ++kk) {
            short8 bfr[4];
#pragma unroll
            for (int ct = 0; ct < 4; ++ct)
                bfr[ct] = *reinterpret_cast<const short8*>(
                    &Bs[(ct * 16 + lr) * BSTR + kk * 32 + lg * 8]);
#pragma unroll
            for (int ct = 0; ct < 4; ++ct)
                acc[ct] = __builtin_amdgcn_mfma_f32_16x16x32_bf16(
                    af[kk], bfr[ct], acc[ct], 0, 0, 0);
        }

        // stage C tile (64x64 bf16) in LDS
#pragma unroll
        for (int reg = 0; reg < 4; ++reg) {
            const int r = w * 16 + lg * 4 + reg;
#pragma unroll
            for (int ct = 0; ct < 4; ++ct)
                Cs[r * CSTR + ct * 16 + lr] = f2bf(acc[ct][reg]);
        }
        __syncthreads();   // Cs complete; all Bs reads complete

        // coalesced copy-out: 8 threads/row, 16B each
        const int n0 = head * 64;
        {
            const int cc = (t & 7) * 8;
#pragma unroll
            for (int it = 0; it < 2; ++it) {
                const int r  = (t >> 3) + it * 32;
                const int gm = blockIdx.x * 64 + r;
                if (gm < M) {
                    const u16x8 val = *reinterpret_cast<const u16x8*>(&Cs[r * CSTR + cc]);
                    *reinterpret_cast<u16x8*>(&Cb[(size_t)gm * HGAT_HC + n0 + cc]) = val;
                }
            }
        }

        if (head < HGAT_H - 1) {   // commit prefetched panel
            ushort_t* dst = &Bs[srow * BSTR + cbase];
#pragma unroll
            for (int j = 0; j < NPF; ++j)
                *reinterpret_cast<u16x8*>(dst + j * 8) = pf[j];
        }
        __syncthreads();   // new Bs panel visible; Cs free for next head
    }
}

// ---------------------------------------------------------------------------
// CSR build: degree count, hierarchical scan, cursor fill.
// ---------------------------------------------------------------------------
__global__ __launch_bounds__(256) void count_deg_kernel(
    const int* __restrict__ ei, int* __restrict__ deg, int E)
{
    const int e = blockIdx.x * 256 + threadIdx.x;
    if (e < E) atomicAdd(&deg[ei[E + e]], 1);
}

__global__ __launch_bounds__(256) void block_sum_kernel(
    const int* __restrict__ deg, int* __restrict__ bsum, int N)
{
    __shared__ int sm[256];
    const int idx = blockIdx.x * 256 + threadIdx.x;
    sm[threadIdx.x] = idx < N ? deg[idx] : 0;
    __syncthreads();
#pragma unroll
    for (int off = 128; off; off >>= 1) {
        if (threadIdx.x < off) sm[threadIdx.x] += sm[threadIdx.x + off];
        __syncthreads();
    }
    if (threadIdx.x == 0) bsum[blockIdx.x] = sm[0];
}

__global__ __launch_bounds__(256) void scan_bsums_kernel(
    int* __restrict__ bsum, int NB)
{
    __shared__ int sm[256];
    const int t = threadIdx.x;
    int v = t < NB ? bsum[t] : 0;
    sm[t] = v;
    __syncthreads();
#pragma unroll
    for (int off = 1; off < 256; off <<= 1) {
        const int u = (t >= off) ? sm[t - off] : 0;
        __syncthreads();
        sm[t] += u;
        __syncthreads();
    }
    if (t < NB) bsum[t] = sm[t] - v;   // exclusive
}

__global__ __launch_bounds__(256) void rowptr_kernel(
    const int* __restrict__ deg, const int* __restrict__ bsum,
    int* __restrict__ rowptr, int* __restrict__ cursor, int N)
{
    __shared__ int sm[256];
    const int t   = threadIdx.x;
    const int idx = blockIdx.x * 256 + t;
    const int v   = idx < N ? deg[idx] : 0;
    sm[t] = v;
    __syncthreads();
#pragma unroll
    for (int off = 1; off < 256; off <<= 1) {
        const int u = (t >= off) ? sm[t - off] : 0;
        __syncthreads();
        sm[t] += u;
        __syncthreads();
    }
    const int base = bsum[blockIdx.x];
    if (idx < N) {
        const int r = base + sm[t] - v;
        rowptr[idx] = r;
        cursor[idx] = r;
    }
    if (idx == N - 1) rowptr[N] = base + sm[t];
}

__global__ __launch_bounds__(256) void fill_csr_kernel(
    const int* __restrict__ ei, int* __restrict__ cursor,
    int* __restrict__ colsrc, int E)
{
    const int e = blockIdx.x * 256 + threadIdx.x;
    if (e >= E) return;
    const int d = ei[E + e];
    const int pos = atomicAdd(&cursor[d], 1);
    colsrc[pos] = ei[e];
}

// ---------------------------------------------------------------------------
// CSR aggregate (round-10 version: per-lane scalar a_src broadcast loads,
// uint2 gather, f32x2 accumulate, exp2 with pre-scaled logits, 4-wide
// edge unroll). Wave per dst node.
// MODE 0: concat + bias + ELU -> bf16 out[N,256].
// MODE 1: head-mean + bias + ELU -> bf16 out[N,64].
// ---------------------------------------------------------------------------
template <int MODE>
__global__ __launch_bounds__(256) void aggregate_csr_kernel(
    const int* __restrict__ rowptr, const int* __restrict__ colsrc,
    const ushort_t* __restrict__ hb, const float* __restrict__ a_src,
    const float* __restrict__ a_dst, const float* __restrict__ bias,
    ushort_t* __restrict__ out, int N)
{
    const int d    = (blockIdx.x * 256 + threadIdx.x) >> 6;
    const int lane = threadIdx.x & 63;
    if (d >= N) return;
    const int h  = lane >> 4;
    const int c0 = lane * 4;
    const float ad = a_dst[d * 4 + h];

    f32x2 acc01 = {0.f, 0.f}, acc23 = {0.f, 0.f};
    float den = 0.f;

    const int beg = rowptr[d], end = rowptr[d + 1];
    int i = beg;
    for (; i + 4 <= end; i += 4) {
        int   sv[4];
        float av[4];
        uint2 qv[4];
#pragma unroll
        for (int j = 0; j < 4; ++j) sv[j] = colsrc[i + j];
#pragma unroll
        for (int j = 0; j < 4; ++j) av[j] = a_src[sv[j] * 4 + h];
#pragma unroll
        for (int j = 0; j < 4; ++j)
            qv[j] = *reinterpret_cast<const uint2*>(&hb[(size_t)sv[j] * HGAT_HC + c0]);
#pragma unroll
        for (int j = 0; j < 4; ++j) {
            float ee = av[j] + ad;
            ee = fmaxf(ee, 0.2f * ee);
            const float wgt = __builtin_amdgcn_exp2f(ee);
            const f32x2 w2 = {wgt, wgt};
            const f32x2 p01 = {bflo(qv[j].x), bfhi(qv[j].x)};
            const f32x2 p23 = {bflo(qv[j].y), bfhi(qv[j].y)};
            acc01 += w2 * p01;
            acc23 += w2 * p23;
            den += wgt;
        }
    }
    for (; i < end; ++i) {
        const int s = colsrc[i];
        float ee = a_src[s * 4 + h] + ad;
        ee = fmaxf(ee, 0.2f * ee);
        const float wgt = __builtin_amdgcn_exp2f(ee);
        const uint2 q = *reinterpret_cast<const uint2*>(&hb[(size_t)s * HGAT_HC + c0]);
        const f32x2 w2 = {wgt, wgt};
        const f32x2 p01 = {bflo(q.x), bfhi(q.x)};
        const f32x2 p23 = {bflo(q.y), bfhi(q.y)};
        acc01 += w2 * p01;
        acc23 += w2 * p23;
        den += wgt;
    }
    {   // self loop
        float ee = a_src[d * 4 + h] + ad;
        ee = fmaxf(ee, 0.2f * ee);
        const float wgt = __builtin_amdgcn_exp2f(ee);
        const uint2 q = *reinterpret_cast<const uint2*>(&hb[(size_t)d * HGAT_HC + c0]);
        const f32x2 w2 = {wgt, wgt};
        const f32x2 p01 = {bflo(q.x), bfhi(q.x)};
        const f32x2 p23 = {bflo(q.y), bfhi(q.y)};
        acc01 += w2 * p01;
        acc23 += w2 * p23;
        den += wgt;
    }

    const float inv = 1.0f / den;
    float4 v = {acc01.x * inv, acc01.y * inv, acc23.x * inv, acc23.y * inv};

    if (MODE == 0) {
        v.x += bias[c0 + 0]; v.y += bias[c0 + 1];
        v.z += bias[c0 + 2]; v.w += bias[c0 + 3];
        v.x = v.x > 0.f ? v.x : expm1f(v.x);
        v.y = v.y > 0.f ? v.y : expm1f(v.y);
        v.z = v.z > 0.f ? v.z : expm1f(v.z);
        v.w = v.w > 0.f ? v.w : expm1f(v.w);
        ushort4 u;
        u.x = f2bf(v.x); u.y = f2bf(v.y); u.z = f2bf(v.z); u.w = f2bf(v.w);
        *reinterpret_cast<ushort4*>(&out[(size_t)d * HGAT_HC + c0]) = u;
    } else {
        v.x += __shfl_xor(v.x, 16); v.x += __shfl_xor(v.x, 32);
        v.y += __shfl_xor(v.y, 16); v.y += __shfl_xor(v.y, 32);
        v.z += __shfl_xor(v.z, 16); v.z += __shfl_xor(v.z, 32);
        v.w += __shfl_xor(v.w, 16); v.w += __shfl_xor(v.w, 32);
        if (lane < 16) {
            const int c = lane * 4;
            float4 r;
            r.x = 0.25f * v.x + bias[c + 0];
            r.y = 0.25f * v.y + bias[c + 1];
            r.z = 0.25f * v.z + bias[c + 2];
            r.w = 0.25f * v.w + bias[c + 3];
            r.x = r.x > 0.f ? r.x : expm1f(r.x);
            r.y = r.y > 0.f ? r.y : expm1f(r.y);
            r.z = r.z > 0.f ? r.z : expm1f(r.z);
            r.w = r.w > 0.f ? r.w : expm1f(r.w);
            ushort4 u;
            u.x = f2bf(r.x); u.y = f2bf(r.y); u.z = f2bf(r.z); u.w = f2bf(r.w);
            *reinterpret_cast<ushort4*>(&out[(size_t)d * HGAT_C + c]) = u;
        }
    }
}

// ---------------------------------------------------------------------------
// Pool stage A: 8 node-slices per graph -> partial sums.
// ---------------------------------------------------------------------------
__device__ __forceinline__ int lower_bound_batch(
    const int* __restrict__ batch, int N, int key)
{
    int lo = 0, hi = N;
    while (lo < hi) {
        const int mid = (lo + hi) >> 1;
        if (batch[mid] < key) lo = mid + 1; else hi = mid;
    }
    return lo;
}

__global__ __launch_bounds__(256) void pool_partial_kernel(
    const ushort_t* __restrict__ hfin, const int* __restrict__ batch,
    float* __restrict__ partial, int N)
{
    const int g   = blockIdx.x >> 3;
    const int s   = blockIdx.x & 7;
    const int t   = threadIdx.x;
    const int c   = t & 63;
    const int sub = t >> 6;

    const int beg = lower_bound_batch(batch, N, g);
    const int end = lower_bound_batch(batch, N, g + 1);
    const int len = end - beg;
    const int sl  = (len + 7) >> 3;
    const int sb  = beg + s * sl;
    const int se  = sb + sl < end ? sb + sl : end;

    float acc = 0.f;
    for (int n = sb + sub; n < se; n += 4)
        acc += bf2f(hfin[(size_t)n * HGAT_C + c]);

    __shared__ float sm[256];
    sm[t] = acc;
    __syncthreads();
    if (sub == 0)
        partial[(size_t)(g * 8 + s) * HGAT_C + c] =
            sm[c] + sm[64 + c] + sm[128 + c] + sm[192 + c];
}

// ---------------------------------------------------------------------------
// Pool stage B fused with final linear: one block per graph.
// ---------------------------------------------------------------------------
__global__ __launch_bounds__(64) void pool_final_fused_kernel(
    const float* __restrict__ partial, const int* __restrict__ batch,
    const float* __restrict__ Wa, const float* __restrict__ ba,
    float* __restrict__ out, int N)
{
    const int g = blockIdx.x;
    const int c = threadIdx.x;
    const int beg = lower_bound_batch(batch, N, g);
    const int end = lower_bound_batch(batch, N, g + 1);
    float s = 0.f;
#pragma unroll
    for (int k = 0; k < 8; ++k)
        s += partial[(size_t)(g * 8 + k) * HGAT_C + c];
    s /= fmaxf((float)(end - beg), 1.0f);

    __shared__ float pr[HGAT_C];
    pr[c] = s;
    __syncthreads();
    if (c < NACT) {
        float o = ba[c];
#pragma unroll
        for (int cc = 0; cc < HGAT_C; ++cc)
            o += pr[cc] * Wa[cc * NACT + c];
        out[g * NACT + c] = o;
    }
}

// ---------------------------------------------------------------------------
extern "C" void kernel_launch(void* const* d_in, const int* in_sizes, int n_in,
                              void* d_out, int out_size, void* d_ws, size_t ws_size,
                              hipStream_t stream)
{
    const float* x     = (const float*)d_in[0];
    const int*   ei    = (const int*)d_in[1];
    const int*   batch = (const int*)d_in[2];
    const float* W1    = (const float*)d_in[5];
    const float* as1   = (const float*)d_in[6];
    const float* ad1   = (const float*)d_in[7];
    const float* b1    = (const float*)d_in[8];
    const float* W2    = (const float*)d_in[9];
    const float* as2   = (const float*)d_in[10];
    const float* ad2   = (const float*)d_in[11];
    const float* b2    = (const float*)d_in[12];
    const float* Wa    = (const float*)d_in[13];
    const float* ba    = (const float*)d_in[14];

    const int N = in_sizes[0] / FIN;
    const int E = in_sizes[1] / 2;

    char* ws = (char*)d_ws;
    size_t off = 0;
    auto alloc = [&](size_t bytes) -> void* {
        void* p = ws + off;
        off += (bytes + 255) & ~(size_t)255;
        return p;
    };
    ushort_t* hb      = (ushort_t*)alloc((size_t)N * HGAT_HC * 2);
    ushort_t* hpost   = (ushort_t*)alloc((size_t)N * HGAT_HC * 2);
    ushort_t* Wt1     = (ushort_t*)alloc((size_t)FIN * HGAT_HC * 2);
    ushort_t* Wt2     = (ushort_t*)alloc((size_t)HGAT_HC * HGAT_HC * 2);
    ushort_t* attBt1  = (ushort_t*)alloc((size_t)16 * FIN * 2);
    ushort_t* attBt2  = (ushort_t*)alloc((size_t)16 * HGAT_HC * 2);
    float*    a_src   = (float*)alloc((size_t)N * 4 * 4);
    float*    a_dst   = (float*)alloc((size_t)N * 4 * 4);
    int*      rowptr  = (int*)alloc((size_t)(N + 1) * 4);
    int*      colsrc  = (int*)alloc((size_t)E * 4);
    int*      deg     = (int*)alloc((size_t)N * 4);
    int*      cursor  = (int*)alloc((size_t)N * 4);
    int*      bsum    = (int*)alloc(256 * 4);
    float*    partial = (float*)alloc((size_t)NGRAPHS * 8 * HGAT_C * 4);
    ushort_t* hfin    = hpost;
    (void)ws_size; (void)n_in; (void)out_size;

    const int gemmBlocks     = (N + 63) / 64;
    const int edgeBlocks     = (E + 255) / 256;
    const int nodeWaveBlocks = (N + 3) / 4;
    const int NB             = (N + 255) / 256;

    // ---------------- CSR build ----------------
    hipMemsetAsync(deg, 0, (size_t)N * 4, stream);
    count_deg_kernel<<<edgeBlocks, 256, 0, stream>>>(ei, deg, E);
    block_sum_kernel<<<NB, 256, 0, stream>>>(deg, bsum, N);
    scan_bsums_kernel<<<1, 256, 0, stream>>>(bsum, NB);
    rowptr_kernel<<<NB, 256, 0, stream>>>(deg, bsum, rowptr, cursor, N);
    fill_csr_kernel<<<edgeBlocks, 256, 0, stream>>>(ei, cursor, colsrc, E);

    // ---------------- weight transpose/cast + att fold ----------------
    wcast2_kernel<<<(FIN * HGAT_HC + HGAT_HC * HGAT_HC + 255) / 256, 256, 0, stream>>>(
        W1, W2, Wt1, Wt2);
    att_fold_kernel<<<((FIN + HGAT_HC) * 8 + 255) / 256, 256, 0, stream>>>(
        W1, as1, ad1, W2, as2, ad2, attBt1, attBt2);

    // ---------------- layer 1 ----------------
    gemm_mfma_att_kernel<FIN, true><<<gemmBlocks, 256, 0, stream>>>(
        x, Wt1, attBt1, hb, a_src, a_dst, N);
    aggregate_csr_kernel<0><<<nodeWaveBlocks, 256, 0, stream>>>(
        rowptr, colsrc, hb, a_src, a_dst, b1, hpost, N);

    // ---------------- layer 2 ----------------
    gemm_mfma_att_kernel<HGAT_HC, false><<<gemmBlocks, 256, 0, stream>>>(
        hpost, Wt2, attBt2, hb, a_src, a_dst, N);
    aggregate_csr_kernel<1><<<nodeWaveBlocks, 256, 0, stream>>>(
        rowptr, colsrc, hb, a_src, a_dst, b2, hfin, N);

    // ---------------- pool + final ----------------
    pool_partial_kernel<<<NGRAPHS * 8, 256, 0, stream>>>(hfin, batch, partial, N);
    pool_final_fused_kernel<<<NGRAPHS, 64, 0, stream>>>(
        partial, batch, Wa, ba, (float*)d_out, N);
}